// Round 11
// baseline (137.094 us; speedup 1.0000x reference)
//
#include <hip/hip_runtime.h>
#include <math.h>

#define BB  16
#define TT  12
#define T2C 10
#define NN  300
#define DD  64
#define M3  900   // 3*NN
#define NW  (BB*T2C)

typedef _Float16 f16;
typedef __attribute__((ext_vector_type(8)))  _Float16 f16x8;
typedef __attribute__((ext_vector_type(16))) float    f32x16;

#define KS 72   // fp16 row stride (144 B)

static __device__ inline unsigned pk2(f16 a, f16 b) {
    union { f16 h[2]; unsigned u; } x; x.h[0] = a; x.h[1] = b; return x.u;
}

// ---------------------------------------------------------------------------
// k_prep (r9-verified): blk < 960: invn + per-chunk tsum partials (no atomics).
// blk == 960: sigw + w1/w2 -> MFMA A-fragment order (fp16) in global.
// ---------------------------------------------------------------------------
__global__ __launch_bounds__(256) void k_prep(const float* __restrict__ feat,
                                              const float* __restrict__ weights,
                                              const float* __restrict__ w1,
                                              const float* __restrict__ w2,
                                              float* __restrict__ sigw,
                                              float* __restrict__ invn,
                                              float* __restrict__ tspart,
                                              f16* __restrict__ w1f,
                                              f16* __restrict__ w2f) {
    int blk = blockIdx.x;
    int tid = threadIdx.x;

    if (blk == BB * TT * 5) {
        if (tid < 64) sigw[tid] = 1.0f / (1.0f + expf(-weights[tid]));
        for (int p = tid; p < 1024; p += 256) {
            int lane = p & 63, s = p >> 6;
            int mat = s >> 3, loc = s & 7, ct = loc >> 2, ks = loc & 3;
            int hcol = ct * 32 + (lane & 31);
            const float* w = mat ? w2 : w1;
            f16* dst = (mat ? w2f : w1f) + ((size_t)loc * 64 + lane) * 8;
            f16x8 v;
            #pragma unroll
            for (int j = 0; j < 8; j++) {
                int d = ks * 16 + 8 * (lane >> 5) + j;
                v[j] = (f16)w[d * DD + hcol];
            }
            *(f16x8*)dst = v;
        }
        return;
    }

    __shared__ float part[4][64];
    int bt = blk / 5, ch = blk % 5;
    int row0 = bt * NN + ch * 60;
    int w = tid >> 6, lane = tid & 63;
    int r16 = lane >> 4, c4 = lane & 15;

    float4 wv = *(const float4*)(weights + c4 * 4);
    float4 sg;
    sg.x = 1.0f / (1.0f + expf(-wv.x)); sg.y = 1.0f / (1.0f + expf(-wv.y));
    sg.z = 1.0f / (1.0f + expf(-wv.z)); sg.w = 1.0f / (1.0f + expf(-wv.w));

    float ax = 0.f, ay = 0.f, az = 0.f, aw = 0.f;
    for (int g = w; g < 15; g += 4) {
        int row = row0 + g * 4 + r16;
        float4 f = *(const float4*)(feat + (size_t)row * DD + c4 * 4);
        float xx = f.x * sg.x, xy = f.y * sg.y, xz = f.z * sg.z, xw = f.w * sg.w;
        float ss = xx * xx + xy * xy + xz * xz + xw * xw;
        ss += __shfl_xor(ss, 1, 64);
        ss += __shfl_xor(ss, 2, 64);
        ss += __shfl_xor(ss, 4, 64);
        ss += __shfl_xor(ss, 8, 64);
        float in = 1.0f / fmaxf(sqrtf(ss), 1e-12f);
        if (c4 == 0) invn[row] = in;
        ax += f.x * in; ay += f.y * in; az += f.z * in; aw += f.w * in;
    }
    #pragma unroll
    for (int off = 16; off <= 32; off <<= 1) {
        ax += __shfl_xor(ax, off, 64); ay += __shfl_xor(ay, off, 64);
        az += __shfl_xor(az, off, 64); aw += __shfl_xor(aw, off, 64);
    }
    if (r16 == 0) {
        float* p = &part[w][c4 * 4];
        p[0] = ax * sg.x; p[1] = ay * sg.y; p[2] = az * sg.z; p[3] = aw * sg.w;
    }
    __syncthreads();
    if (tid < 64)
        tspart[(size_t)blk * 64 + tid] =
            part[0][tid] + part[1][tid] + part[2][tid] + part[3][tid];
}

// ---------------------------------------------------------------------------
// k_agg2: m-split aggregation. Block = (window, 64-row n-tile, m-chunk mc).
// mc=0: rows 0..447 (7 kt), mc=1: rows 448..899 (8 kt, masked at 900).
// r7-verified 4-barrier kt loop. Writes UN-normalized fp32 partial acc:
// mc=0 -> part0 (d_out), mc=1 -> part1 (ws). Grid 1600 -> 6.25 blocks/CU,
// 5 resident by LDS (27.6 KB): barrier stalls finally overlap.
// ---------------------------------------------------------------------------
__global__ __launch_bounds__(256) void k_agg2(const float* __restrict__ feat,
                                              const float* __restrict__ sigw,
                                              const float* __restrict__ invn,
                                              float* __restrict__ part0,
                                              float* __restrict__ part1) {
    __shared__ f16 Kf[64 * KS];
    __shared__ f16 Vt[64 * KS];
    __shared__ f16 Sl[64 * KS];

    int blk = blockIdx.x;
    int wdw = blk % NW;          // XCD swizzle: window's blocks are 160 apart
    int rest = blk / NW;
    int ntile = rest % 5;
    int mc = rest / 5;
    int t2 = wdw % T2C, b = wdw / T2C;
    int n0 = ntile * 64;
    int qrow0 = (b * TT + t2 + 2) * NN;
    int krow0 = (b * TT + t2) * NN + mc * 448;
    int Lm  = mc ? (M3 - 448) : 448;   // valid rows in this chunk (452 / 448)
    int kts = mc ? 8 : 7;

    int tid = threadIdx.x;
    int wv = tid >> 6, lane = tid & 63;
    int l31 = lane & 31, lh = lane >> 5;
    int nt = wv & 1;   // phase1 n-block == phase2 row-block
    int mt = wv >> 1;  // phase1 m-tile  == phase2 d-block

    // ---- Q'' B-frags in registers: feat_q * sigw^2 * invn_q ----
    f16x8 qf[4];
    {
        int nloc = n0 + nt * 32 + l31;
        bool ok = nloc < NN;
        int gr = qrow0 + (ok ? nloc : 0);
        float in = ok ? invn[gr] : 0.f;
        #pragma unroll
        for (int ks = 0; ks < 4; ks++) {
            int c0 = ks * 16 + 8 * lh;
            float4 f0 = *(const float4*)(feat + (size_t)gr * DD + c0);
            float4 f1 = *(const float4*)(feat + (size_t)gr * DD + c0 + 4);
            float4 s0 = *(const float4*)(sigw + c0);
            float4 s1 = *(const float4*)(sigw + c0 + 4);
            f16x8 qv;
            qv[0] = (f16)(f0.x * s0.x * s0.x * in); qv[1] = (f16)(f0.y * s0.y * s0.y * in);
            qv[2] = (f16)(f0.z * s0.z * s0.z * in); qv[3] = (f16)(f0.w * s0.w * s0.w * in);
            qv[4] = (f16)(f1.x * s1.x * s1.x * in); qv[5] = (f16)(f1.y * s1.y * s1.y * in);
            qv[6] = (f16)(f1.z * s1.z * s1.z * in); qv[7] = (f16)(f1.w * s1.w * s1.w * in);
            qf[ks] = qv;
        }
    }

    f32x16 acc;
    #pragma unroll
    for (int i = 0; i < 16; i++) acc[i] = 0.f;

    int mrow_s = (tid & 31) * 2;     // staging m-pair
    int dblk_s = (tid >> 5) * 8;     // staging 8-col block

    for (int kt = 0; kt < kts; kt++) {
        int m0 = kt * 64;
        __syncthreads();             // prev phase2 done with Kf/Vt/Sl

        // ---- stage Kf (raw feat fp16); keep scaled V values in regs ----
        f16 vv[2][8];
        #pragma unroll
        for (int pi = 0; pi < 2; pi++) {
            int mloc = mrow_s + pi, gm = m0 + mloc;
            float4 fa = make_float4(0, 0, 0, 0), fb = make_float4(0, 0, 0, 0);
            float in = 0.f;
            if (gm < Lm) {
                int gr = krow0 + gm;
                in = invn[gr];
                fa = *(const float4*)(feat + (size_t)gr * DD + dblk_s);
                fb = *(const float4*)(feat + (size_t)gr * DD + dblk_s + 4);
            }
            f16x8 kr;
            kr[0] = (f16)fa.x; kr[1] = (f16)fa.y; kr[2] = (f16)fa.z; kr[3] = (f16)fa.w;
            kr[4] = (f16)fb.x; kr[5] = (f16)fb.y; kr[6] = (f16)fb.z; kr[7] = (f16)fb.w;
            *(f16x8*)&Kf[mloc * KS + dblk_s] = kr;
            vv[pi][0] = (f16)(fa.x * in); vv[pi][1] = (f16)(fa.y * in);
            vv[pi][2] = (f16)(fa.z * in); vv[pi][3] = (f16)(fa.w * in);
            vv[pi][4] = (f16)(fb.x * in); vv[pi][5] = (f16)(fb.y * in);
            vv[pi][6] = (f16)(fb.z * in); vv[pi][7] = (f16)(fb.w * in);
        }
        __syncthreads();

        // ---- phase1: S''^T tile (m-rows mt*32.., n-cols nt*32..) ----
        f32x16 c1;
        #pragma unroll
        for (int i = 0; i < 16; i++) c1[i] = 0.f;
        #pragma unroll
        for (int ks = 0; ks < 4; ks++) {
            f16x8 af = *(const f16x8*)&Kf[(mt * 32 + l31) * KS + ks * 16 + 8 * lh];
            c1 = __builtin_amdgcn_mfma_f32_32x32x16_f16(af, qf[ks], c1, 0, 0, 0);
        }
        #pragma unroll
        for (int g = 0; g < 4; g++) {
            union { f16 h[4]; uint2 u; } p;
            p.h[0] = (f16)c1[4 * g + 0]; p.h[1] = (f16)c1[4 * g + 1];
            p.h[2] = (f16)c1[4 * g + 2]; p.h[3] = (f16)c1[4 * g + 3];
            *(uint2*)&Sl[(nt * 32 + l31) * KS + mt * 32 + 8 * g + 4 * lh] = p.u;
        }
        __syncthreads();             // Kf reads + Sl writes done

        // ---- stage Vt (feat*invn transposed) from regs ----
        #pragma unroll
        for (int i = 0; i < 8; i++)
            *(unsigned*)&Vt[(dblk_s + i) * KS + mrow_s] = pk2(vv[0][i], vv[1][i]);
        __syncthreads();

        // ---- phase2: acc(n-block nt, d-block mt) += S . V ----
        #pragma unroll
        for (int ms = 0; ms < 4; ms++) {
            f16x8 sa = *(const f16x8*)&Sl[(nt * 32 + l31) * KS + ms * 16 + 8 * lh];
            f16x8 vb = *(const f16x8*)&Vt[(mt * 32 + l31) * KS + ms * 16 + 8 * lh];
            acc = __builtin_amdgcn_mfma_f32_32x32x16_f16(sa, vb, acc, 0, 0, 0);
        }
    }

    // ---- store un-normalized partial ----
    float* pb = mc ? part1 : part0;
    int dcol = mt * 32 + l31;
    #pragma unroll
    for (int g = 0; g < 4; g++) {
        #pragma unroll
        for (int i = 0; i < 4; i++) {
            int rl = nt * 32 + 8 * g + 4 * lh + i;
            int n = n0 + rl;
            if (n < NN)
                pb[((size_t)wdw * NN + n) * DD + dcol] = acc[4 * g + i];
        }
    }
}

// ---------------------------------------------------------------------------
// k_ffn: block = (window, 60-row tile) -> never straddles a window.
// Sums the two partials, computes deg from tspart basis, normalizes, then
// the r7-verified FFN + residual + LayerNorm tail. In-place on d_out (part0).
// ---------------------------------------------------------------------------
__global__ __launch_bounds__(256) void k_ffn(const float* __restrict__ part0,
                                             const float* __restrict__ part1,
                                             const float* __restrict__ feat,
                                             const float* __restrict__ sigw,
                                             const float* __restrict__ invn,
                                             const float* __restrict__ tspart,
                                             const f16* __restrict__ w1f,
                                             const f16* __restrict__ w2f,
                                             const float* __restrict__ b1,
                                             const float* __restrict__ b2,
                                             const float* __restrict__ gamma,
                                             const float* __restrict__ beta,
                                             float* __restrict__ out) {
    __shared__ float Ol[64 * 68];
    __shared__ f16 Hl[64 * KS];
    __shared__ float red[64][4][2];
    __shared__ float rmax[64][4];
    __shared__ float scls[64];
    __shared__ float isls[64];
    __shared__ float degp[64][4];
    __shared__ float ksumL[64];

    int blk = blockIdx.x;
    int wdw = blk % NW;          // XCD-consistent with k_agg2 partial locality
    int tl  = blk / NW;
    int t2 = wdw % T2C, b = wdw / T2C;
    int n0 = tl * 60;
    int tid = threadIdx.x;
    int wv = tid >> 6, lane = tid & 63;
    int l31 = lane & 31, lh = lane >> 5;
    int ct = wv & 1, rt = wv >> 1;
    int r = tid >> 2, q = tid & 3, c0 = q * 16;

    // ---- ksumL (deg basis) ----
    if (tid < 64) {
        const float* tp = tspart + (size_t)(b * TT + t2) * 5 * 64 + tid;
        float s = 0.f;
        #pragma unroll
        for (int j = 0; j < 15; j++) s += tp[j * 64];
        ksumL[tid] = s;
    }

    // ---- weight A-frags (global, L2-hot) ----
    f16x8 w1a[4], w2a[4];
    #pragma unroll
    for (int ks = 0; ks < 4; ks++) {
        w1a[ks] = *(const f16x8*)(w1f + ((size_t)(ct * 4 + ks) * 64 + lane) * 8);
        w2a[ks] = *(const f16x8*)(w2f + ((size_t)(ct * 4 + ks) * 64 + lane) * 8);
    }

    // ---- rows: sum partials; load feat (residual + deg dot) ----
    int n = n0 + r;
    int nc = (n < NN) ? n : (NN - 1);     // clamp pad rows (finite, discarded)
    size_t prow = ((size_t)wdw * NN + nc) * DD + c0;
    size_t frow = ((size_t)(b * TT + t2 + 2) * NN + nc) * DD;
    float invq = invn[(size_t)(b * TT + t2 + 2) * NN + nc];
    float pv[16], fv[16];
    #pragma unroll
    for (int i = 0; i < 4; i++) {
        float4 p0 = *(const float4*)(part0 + prow + 4 * i);
        float4 p1 = *(const float4*)(part1 + prow + 4 * i);
        pv[4*i+0] = p0.x + p1.x; pv[4*i+1] = p0.y + p1.y;
        pv[4*i+2] = p0.z + p1.z; pv[4*i+3] = p0.w + p1.w;
        float4 f = *(const float4*)(feat + frow + c0 + 4 * i);
        fv[4*i+0] = f.x; fv[4*i+1] = f.y; fv[4*i+2] = f.z; fv[4*i+3] = f.w;
    }
    __syncthreads();   // ksumL visible

    // ---- deg partial dot over this thread's 16 cols ----
    {
        float p = 0.f;
        #pragma unroll
        for (int i = 0; i < 4; i++) {
            float4 s = *(const float4*)(sigw + c0 + 4 * i);
            float4 k = *(const float4*)(ksumL + c0 + 4 * i);
            p += fv[4*i+0] * s.x * k.x + fv[4*i+1] * s.y * k.y
               + fv[4*i+2] * s.z * k.z + fv[4*i+3] * s.w * k.w;
        }
        degp[r][q] = p;
    }
    __syncthreads();

    // ---- normalize, stage Ol, per-row absmax ----
    {
        float dg = (degp[r][0] + degp[r][1] + degp[r][2] + degp[r][3]) * invq;
        float dinv = (dg == 0.f) ? 0.f : 1.f / dg;
        float mx = 0.f;
        #pragma unroll
        for (int i = 0; i < 16; i++) {
            float a = pv[i] * dinv;
            pv[i] = a;
            mx = fmaxf(mx, fabsf(a));
        }
        #pragma unroll
        for (int i = 0; i < 4; i++)
            *(float4*)&Ol[r * 68 + c0 + 4 * i] =
                make_float4(pv[4*i+0], pv[4*i+1], pv[4*i+2], pv[4*i+3]);
        rmax[r][q] = mx;
    }
    __syncthreads();
    if (q == 0) {
        float rm = fmaxf(fmaxf(rmax[r][0], rmax[r][1]),
                         fmaxf(rmax[r][2], rmax[r][3]));
        int e = 0;
        frexpf(rm, &e);
        scls[r] = (rm > 1.f) ? exp2f((float)-e) : 1.f;
        isls[r] = (rm > 1.f) ? exp2f((float)e) : 1.f;
    }
    __syncthreads();

    // ---- phase A: h_s^T = w1^T . A_s^T ----
    float sclrow = scls[rt * 32 + l31];
    f32x16 hc;
    #pragma unroll
    for (int i = 0; i < 16; i++) hc[i] = 0.f;
    #pragma unroll
    for (int ks = 0; ks < 4; ks++) {
        const float* prw = &Ol[(rt * 32 + l31) * 68 + ks * 16 + 8 * lh];
        float4 pa = *(const float4*)prw;
        float4 pb = *(const float4*)(prw + 4);
        f16x8 bf;
        bf[0] = (f16)(pa.x * sclrow); bf[1] = (f16)(pa.y * sclrow);
        bf[2] = (f16)(pa.z * sclrow); bf[3] = (f16)(pa.w * sclrow);
        bf[4] = (f16)(pb.x * sclrow); bf[5] = (f16)(pb.y * sclrow);
        bf[6] = (f16)(pb.z * sclrow); bf[7] = (f16)(pb.w * sclrow);
        hc = __builtin_amdgcn_mfma_f32_32x32x16_f16(w1a[ks], bf, hc, 0, 0, 0);
    }
    #pragma unroll
    for (int g = 0; g < 4; g++) {
        union { f16 h[4]; uint2 u; } p;
        #pragma unroll
        for (int i = 0; i < 4; i++) {
            int hcol = ct * 32 + 8 * g + 4 * lh + i;
            p.h[i] = (f16)fmaxf(hc[4 * g + i] + sclrow * b1[hcol], 0.f);
        }
        *(uint2*)&Hl[(rt * 32 + l31) * KS + ct * 32 + 8 * g + 4 * lh] = p.u;
    }
    __syncthreads();

    // ---- phase B: o_s^T = w2^T . h_s^T ; overwrite Ol ----
    f32x16 oc;
    #pragma unroll
    for (int i = 0; i < 16; i++) oc[i] = 0.f;
    #pragma unroll
    for (int ks = 0; ks < 4; ks++) {
        f16x8 bf = *(const f16x8*)&Hl[(rt * 32 + l31) * KS + ks * 16 + 8 * lh];
        oc = __builtin_amdgcn_mfma_f32_32x32x16_f16(w2a[ks], bf, oc, 0, 0, 0);
    }
    __syncthreads();
    #pragma unroll
    for (int g = 0; g < 4; g++) {
        float4 o4 = make_float4(oc[4*g+0], oc[4*g+1], oc[4*g+2], oc[4*g+3]);
        *(float4*)&Ol[(rt * 32 + l31) * 68 + ct * 32 + 8 * g + 4 * lh] = o4;
    }
    __syncthreads();

    // ---- epilogue: s = o_s/s_n + b2 + residual; LayerNorm; store r<60 ----
    float is = isls[r];
    float v[16];
    float sum = 0.f;
    #pragma unroll
    for (int i = 0; i < 16; i++) {
        int c = c0 + i;
        float x = Ol[r * 68 + c] * is + b2[c] + fv[i];
        v[i] = x; sum += x;
    }
    red[r][q][0] = sum;
    __syncthreads();
    float mu = (red[r][0][0] + red[r][1][0] + red[r][2][0] + red[r][3][0]) * (1.f / 64.f);
    float s2 = 0.f;
    #pragma unroll
    for (int i = 0; i < 16; i++) { float d = v[i] - mu; s2 += d * d; }
    red[r][q][1] = s2;
    __syncthreads();
    float var = (red[r][0][1] + red[r][1][1] + red[r][2][1] + red[r][3][1]) * (1.f / 64.f);
    float rs = rsqrtf(var + 1e-5f);
    if (r < 60) {
        size_t grow = (size_t)wdw * NN + n;
        #pragma unroll
        for (int i4 = 0; i4 < 4; i4++) {
            int c = c0 + 4 * i4;
            float4 g4 = *(const float4*)(gamma + c);
            float4 be = *(const float4*)(beta + c);
            float4 o4;
            o4.x = (v[4*i4+0] - mu) * rs * g4.x + be.x;
            o4.y = (v[4*i4+1] - mu) * rs * g4.y + be.y;
            o4.z = (v[4*i4+2] - mu) * rs * g4.z + be.z;
            o4.w = (v[4*i4+3] - mu) * rs * g4.w + be.w;
            *(float4*)(out + grow * DD + c) = o4;
        }
    }
}

// ---------------------------------------------------------------------------
extern "C" void kernel_launch(void* const* d_in, const int* in_sizes, int n_in,
                              void* d_out, int out_size, void* d_ws, size_t ws_size,
                              hipStream_t stream) {
    const float* feat    = (const float*)d_in[0];
    const float* weights = (const float*)d_in[1];
    const float* w1      = (const float*)d_in[2];
    const float* b1      = (const float*)d_in[3];
    const float* w2      = (const float*)d_in[4];
    const float* b2      = (const float*)d_in[5];
    const float* gamma   = (const float*)d_in[6];
    const float* beta    = (const float*)d_in[7];
    float* out = (float*)d_out;

    float* sigw   = (float*)d_ws;                   // 64
    float* invn   = sigw + 64;                      // 57600
    float* tspart = invn + BB * TT * NN;            // 960*64 = 61440
    f16*   w1f    = (f16*)(tspart + 960 * 64);      // 4096 f16
    f16*   w2f    = w1f + 4096;                     // 4096 f16
    float* part1  = (float*)(w2f + 4096);           // 160*300*64 = 3.07M floats
    float* part0  = out;                            // chunk-0 partial, in-place

    k_prep<<<BB * TT * 5 + 1, 256, 0, stream>>>(feat, weights, w1, w2,
                                                sigw, invn, tspart, w1f, w2f);
    k_agg2<<<NW * 10, 256, 0, stream>>>(feat, sigw, invn, part0, part1);
    k_ffn<<<NW * 5, 256, 0, stream>>>(part0, part1, feat, sigw, invn, tspart,
                                      w1f, w2f, b1, b2, gamma, beta, out);
}

// Round 12
// 106.738 us; speedup vs baseline: 1.2844x; 1.2844x over previous
//
#include <hip/hip_runtime.h>
#include <math.h>

#define BB  16
#define TT  12
#define T2C 10
#define NN  300
#define DD  64
#define M3  900   // 3*NN
#define NW  (BB*T2C)

typedef _Float16 f16;
typedef __attribute__((ext_vector_type(8)))  _Float16 f16x8;
typedef __attribute__((ext_vector_type(16))) float    f32x16;

#define KS 72   // fp16 row stride (144 B)

static __device__ inline unsigned pk2(f16 a, f16 b) {
    union { f16 h[2]; unsigned u; } x; x.h[0] = a; x.h[1] = b; return x.u;
}

// ---------------------------------------------------------------------------
// k_prep (r9-verified): blk < 960: invn + per-chunk tsum partials (no atomics).
// blk == 960: sigw + w1/w2 -> MFMA A-fragment order (fp16) in global.
// ---------------------------------------------------------------------------
__global__ __launch_bounds__(256) void k_prep(const float* __restrict__ feat,
                                              const float* __restrict__ weights,
                                              const float* __restrict__ w1,
                                              const float* __restrict__ w2,
                                              float* __restrict__ sigw,
                                              float* __restrict__ invn,
                                              float* __restrict__ tspart,
                                              f16* __restrict__ w1f,
                                              f16* __restrict__ w2f) {
    int blk = blockIdx.x;
    int tid = threadIdx.x;

    if (blk == BB * TT * 5) {
        if (tid < 64) sigw[tid] = 1.0f / (1.0f + expf(-weights[tid]));
        for (int p = tid; p < 1024; p += 256) {
            int lane = p & 63, s = p >> 6;
            int mat = s >> 3, loc = s & 7, ct = loc >> 2, ks = loc & 3;
            int hcol = ct * 32 + (lane & 31);
            const float* w = mat ? w2 : w1;
            f16* dst = (mat ? w2f : w1f) + ((size_t)loc * 64 + lane) * 8;
            f16x8 v;
            #pragma unroll
            for (int j = 0; j < 8; j++) {
                int d = ks * 16 + 8 * (lane >> 5) + j;
                v[j] = (f16)w[d * DD + hcol];
            }
            *(f16x8*)dst = v;
        }
        return;
    }

    __shared__ float part[4][64];
    int bt = blk / 5, ch = blk % 5;
    int row0 = bt * NN + ch * 60;
    int w = tid >> 6, lane = tid & 63;
    int r16 = lane >> 4, c4 = lane & 15;

    float4 wv = *(const float4*)(weights + c4 * 4);
    float4 sg;
    sg.x = 1.0f / (1.0f + expf(-wv.x)); sg.y = 1.0f / (1.0f + expf(-wv.y));
    sg.z = 1.0f / (1.0f + expf(-wv.z)); sg.w = 1.0f / (1.0f + expf(-wv.w));

    float ax = 0.f, ay = 0.f, az = 0.f, aw = 0.f;
    for (int g = w; g < 15; g += 4) {
        int row = row0 + g * 4 + r16;
        float4 f = *(const float4*)(feat + (size_t)row * DD + c4 * 4);
        float xx = f.x * sg.x, xy = f.y * sg.y, xz = f.z * sg.z, xw = f.w * sg.w;
        float ss = xx * xx + xy * xy + xz * xz + xw * xw;
        ss += __shfl_xor(ss, 1, 64);
        ss += __shfl_xor(ss, 2, 64);
        ss += __shfl_xor(ss, 4, 64);
        ss += __shfl_xor(ss, 8, 64);
        float in = 1.0f / fmaxf(sqrtf(ss), 1e-12f);
        if (c4 == 0) invn[row] = in;
        ax += f.x * in; ay += f.y * in; az += f.z * in; aw += f.w * in;
    }
    #pragma unroll
    for (int off = 16; off <= 32; off <<= 1) {
        ax += __shfl_xor(ax, off, 64); ay += __shfl_xor(ay, off, 64);
        az += __shfl_xor(az, off, 64); aw += __shfl_xor(aw, off, 64);
    }
    if (r16 == 0) {
        float* p = &part[w][c4 * 4];
        p[0] = ax * sg.x; p[1] = ay * sg.y; p[2] = az * sg.z; p[3] = aw * sg.w;
    }
    __syncthreads();
    if (tid < 64)
        tspart[(size_t)blk * 64 + tid] =
            part[0][tid] + part[1][tid] + part[2][tid] + part[3][tid];
}

// ---------------------------------------------------------------------------
// k_M: per-timestep gram basis. Mt[bt](c,d) = sum_m feat(m,c)*invn_m*feat(m,d)
// (symmetric 64x64). Stored as Mt[bt][d][c] fp32 (C-layout float4 stores).
// 192 blocks x 5 m-epochs of 64 rows (last masked at 300). Both MFMA operands
// staged transposed from the SAME feat loads (Kti = xinvn, Vtt = raw).
// ---------------------------------------------------------------------------
__global__ __launch_bounds__(256) void k_M(const float* __restrict__ feat,
                                           const float* __restrict__ invn,
                                           float* __restrict__ Mt) {
    __shared__ f16 Kti[64 * KS];   // [c][m] feat*invn
    __shared__ f16 Vtt[64 * KS];   // [d][m] raw feat
    int bt = blockIdx.x;           // 0..191 = b*TT + t
    int row0 = bt * NN;
    int tid = threadIdx.x;
    int wv = tid >> 6, lane = tid & 63;
    int l31 = lane & 31, lh = lane >> 5;
    int ci = wv & 1, di = wv >> 1;

    int mr = (tid & 31) * 2;       // staging m-pair
    int cb = (tid >> 5) * 8;       // staging 8-col block

    f32x16 acc;
    #pragma unroll
    for (int i = 0; i < 16; i++) acc[i] = 0.f;

    for (int ep = 0; ep < 5; ep++) {
        __syncthreads();           // prev epoch reads done
        int gm0 = ep * 64 + mr, gm1 = gm0 + 1;
        bool ok0 = gm0 < NN, ok1 = gm1 < NN;
        int g0 = row0 + (ok0 ? gm0 : 0);
        int g1 = row0 + (ok1 ? gm1 : 0);
        float4 a0 = *(const float4*)(feat + (size_t)g0 * DD + cb);
        float4 a1 = *(const float4*)(feat + (size_t)g0 * DD + cb + 4);
        float4 b0 = *(const float4*)(feat + (size_t)g1 * DD + cb);
        float4 b1 = *(const float4*)(feat + (size_t)g1 * DD + cb + 4);
        float i0 = ok0 ? invn[g0] : 0.f;   // A-side zero kills masked rows
        float i1 = ok1 ? invn[g1] : 0.f;
        float av[8] = {a0.x, a0.y, a0.z, a0.w, a1.x, a1.y, a1.z, a1.w};
        float bv[8] = {b0.x, b0.y, b0.z, b0.w, b1.x, b1.y, b1.z, b1.w};
        #pragma unroll
        for (int i = 0; i < 8; i++) {
            *(unsigned*)&Kti[(cb + i) * KS + mr] = pk2((f16)(av[i] * i0), (f16)(bv[i] * i1));
            *(unsigned*)&Vtt[(cb + i) * KS + mr] = pk2((f16)av[i], (f16)bv[i]);
        }
        __syncthreads();
        #pragma unroll
        for (int ks = 0; ks < 4; ks++) {
            f16x8 af = *(const f16x8*)&Kti[(ci * 32 + l31) * KS + ks * 16 + 8 * lh];
            f16x8 bf = *(const f16x8*)&Vtt[(di * 32 + l31) * KS + ks * 16 + 8 * lh];
            acc = __builtin_amdgcn_mfma_f32_32x32x16_f16(af, bf, acc, 0, 0, 0);
        }
    }
    // C-layout: col = d = di*32+l31, rows c = ci*32 + 8g+4lh+i -> [d][c] float4
    float* mb = Mt + (size_t)bt * 4096;
    #pragma unroll
    for (int g = 0; g < 4; g++)
        *(float4*)&mb[(di * 32 + l31) * 64 + ci * 32 + 8 * g + 4 * lh] =
            make_float4(acc[4 * g + 0], acc[4 * g + 1], acc[4 * g + 2], acc[4 * g + 3]);
}

// ---------------------------------------------------------------------------
// k_U: per (window, 64-row n-tile): M_w = Mt[t2]+Mt[t2+1]+Mt[t2+2] (fp32 sum
// -> fp16 Mh in LDS), U^T = Mh . Q''^T (4 MFMA/wave), deg via tspart basis,
// Ol = U*dinv, then the r7/r11-verified FFN + residual + LayerNorm tail.
// ---------------------------------------------------------------------------
__global__ __launch_bounds__(256) void k_U(const float* __restrict__ feat,
                                           const float* __restrict__ sigw,
                                           const float* __restrict__ invn,
                                           const float* __restrict__ tspart,
                                           const float* __restrict__ Mt,
                                           const f16* __restrict__ w1f,
                                           const f16* __restrict__ w2f,
                                           const float* __restrict__ b1,
                                           const float* __restrict__ b2,
                                           const float* __restrict__ gamma,
                                           const float* __restrict__ beta,
                                           float* __restrict__ out) {
    __shared__ union __align__(16) {
        f16 Mh[64 * KS];           // M_w fp16 [d][c] (U stage)
        f16 Hl[64 * KS];           // FFN hidden (Mh dead by then)
    } MH;
    __shared__ float Ol[64 * 68];
    __shared__ float red[64][4][2];
    __shared__ float rmax[64][4];
    __shared__ float scls[64];
    __shared__ float isls[64];
    __shared__ float degp[64][4];
    __shared__ float degs[64];
    __shared__ float ksumL[64];

    int blk = blockIdx.x;
    int wdw = blk % NW;            // XCD swizzle
    int rb  = blk / NW;
    int t2 = wdw % T2C, b = wdw / T2C;
    int n0 = rb * 64;
    int qrow0 = (b * TT + t2 + 2) * NN;
    int tid = threadIdx.x;
    int wv = tid >> 6, lane = tid & 63;
    int l31 = lane & 31, lh = lane >> 5;
    int nt = wv & 1;   // n-half for U
    int dt = wv >> 1;  // d-half for U
    int ct = wv & 1, rt = wv >> 1;   // FFN roles
    int r = tid >> 2, q = tid & 3, c0 = q * 16;

    // ---- weight A-frags (global, L2-hot; issued early) ----
    f16x8 w1a[4], w2a[4];
    #pragma unroll
    for (int ks = 0; ks < 4; ks++) {
        w1a[ks] = *(const f16x8*)(w1f + ((size_t)(ct * 4 + ks) * 64 + lane) * 8);
        w2a[ks] = *(const f16x8*)(w2f + ((size_t)(ct * 4 + ks) * 64 + lane) * 8);
    }

    // ---- ksumL (deg basis) ----
    if (tid < 64) {
        const float* tp = tspart + (size_t)(b * TT + t2) * 5 * 64 + tid;
        float s = 0.f;
        #pragma unroll
        for (int j = 0; j < 15; j++) s += tp[j * 64];
        ksumL[tid] = s;
    }

    // ---- Q'' B-frags: feat_q * sigw^2 * invn_q (lane row n = n0+nt*32+l31) ----
    f16x8 qf[4];
    {
        int nloc = n0 + nt * 32 + l31;
        bool ok = nloc < NN;
        int gr = qrow0 + (ok ? nloc : 0);
        float in = ok ? invn[gr] : 0.f;
        #pragma unroll
        for (int ks = 0; ks < 4; ks++) {
            int cc = ks * 16 + 8 * lh;
            float4 f0 = *(const float4*)(feat + (size_t)gr * DD + cc);
            float4 f1 = *(const float4*)(feat + (size_t)gr * DD + cc + 4);
            float4 s0 = *(const float4*)(sigw + cc);
            float4 s1 = *(const float4*)(sigw + cc + 4);
            f16x8 qv;
            qv[0] = (f16)(f0.x * s0.x * s0.x * in); qv[1] = (f16)(f0.y * s0.y * s0.y * in);
            qv[2] = (f16)(f0.z * s0.z * s0.z * in); qv[3] = (f16)(f0.w * s0.w * s0.w * in);
            qv[4] = (f16)(f1.x * s1.x * s1.x * in); qv[5] = (f16)(f1.y * s1.y * s1.y * in);
            qv[6] = (f16)(f1.z * s1.z * s1.z * in); qv[7] = (f16)(f1.w * s1.w * s1.w * in);
            qf[ks] = qv;
        }
    }

    // ---- M_w = sum of 3 Mt slabs (fp32; thread = row d=r, 16 c's) ----
    float ms[16];
    {
        const float* mtb = Mt + (size_t)(b * TT + t2) * 4096 + r * 64 + c0;
        #pragma unroll
        for (int i = 0; i < 4; i++) {
            float4 m0 = *(const float4*)(mtb + 4 * i);
            float4 m1 = *(const float4*)(mtb + 4096 + 4 * i);
            float4 m2 = *(const float4*)(mtb + 8192 + 4 * i);
            ms[4*i+0] = m0.x + m1.x + m2.x; ms[4*i+1] = m0.y + m1.y + m2.y;
            ms[4*i+2] = m0.z + m1.z + m2.z; ms[4*i+3] = m0.w + m1.w + m2.w;
        }
    }

    // ---- residual feat rows + invq (row n = n0+r, clamped) ----
    int n = n0 + r;
    int nc = (n < NN) ? n : (NN - 1);
    size_t frow = ((size_t)qrow0 + nc) * DD;
    float fv[16];
    #pragma unroll
    for (int i = 0; i < 4; i++) {
        float4 f = *(const float4*)(feat + frow + c0 + 4 * i);
        fv[4*i+0] = f.x; fv[4*i+1] = f.y; fv[4*i+2] = f.z; fv[4*i+3] = f.w;
    }
    float invq = invn[qrow0 + nc];

    __syncthreads();   // ksumL visible

    // ---- deg partials ----
    {
        float p = 0.f;
        #pragma unroll
        for (int i = 0; i < 4; i++) {
            float4 s = *(const float4*)(sigw + c0 + 4 * i);
            float4 k = *(const float4*)(ksumL + c0 + 4 * i);
            p += fv[4*i+0] * s.x * k.x + fv[4*i+1] * s.y * k.y
               + fv[4*i+2] * s.z * k.z + fv[4*i+3] * s.w * k.w;
        }
        degp[r][q] = p * invq;
    }

    // ---- Mh fp16 [d][c] ----
    #pragma unroll
    for (int hhalf = 0; hhalf < 2; hhalf++) {
        f16x8 v;
        #pragma unroll
        for (int j = 0; j < 8; j++) v[j] = (f16)ms[8 * hhalf + j];
        *(f16x8*)&MH.Mh[r * KS + c0 + 8 * hhalf] = v;
    }
    __syncthreads();   // Mh + degp visible

    if (tid < 64)
        degs[tid] = degp[tid][0] + degp[tid][1] + degp[tid][2] + degp[tid][3];

    // ---- U^T tile: D[d][n] = sum_c M(c,d) Q''(n,c)  (M symmetric) ----
    f32x16 ua;
    #pragma unroll
    for (int i = 0; i < 16; i++) ua[i] = 0.f;
    #pragma unroll
    for (int ks = 0; ks < 4; ks++) {
        f16x8 af = *(const f16x8*)&MH.Mh[(dt * 32 + l31) * KS + ks * 16 + 8 * lh];
        ua = __builtin_amdgcn_mfma_f32_32x32x16_f16(af, qf[ks], ua, 0, 0, 0);
    }
    __syncthreads();   // degs visible; Mh reads done (Hl may overwrite later)

    // ---- Ol[n][d] = U * dinv  (lane col n = nt*32+l31; rows d consecutive) ----
    {
        int nl = nt * 32 + l31;
        float dg = degs[nl];
        float dinv = (dg == 0.f) ? 0.f : 1.f / dg;
        #pragma unroll
        for (int g = 0; g < 4; g++)
            *(float4*)&Ol[nl * 68 + dt * 32 + 8 * g + 4 * lh] =
                make_float4(ua[4*g+0] * dinv, ua[4*g+1] * dinv,
                            ua[4*g+2] * dinv, ua[4*g+3] * dinv);
    }
    __syncthreads();

    // ---- per-row pow2 scale ----
    {
        float mx = 0.f;
        #pragma unroll
        for (int i = 0; i < 16; i += 4) {
            float4 f = *(const float4*)&Ol[r * 68 + c0 + i];
            mx = fmaxf(mx, fmaxf(fmaxf(fabsf(f.x), fabsf(f.y)),
                                 fmaxf(fabsf(f.z), fabsf(f.w))));
        }
        rmax[r][q] = mx;
    }
    __syncthreads();
    if (q == 0) {
        float rm = fmaxf(fmaxf(rmax[r][0], rmax[r][1]),
                         fmaxf(rmax[r][2], rmax[r][3]));
        int e = 0;
        frexpf(rm, &e);
        scls[r] = (rm > 1.f) ? exp2f((float)-e) : 1.f;
        isls[r] = (rm > 1.f) ? exp2f((float)e) : 1.f;
    }
    __syncthreads();

    // ---- phase A: h_s^T = w1^T . A_s^T ----
    float sclrow = scls[rt * 32 + l31];
    f32x16 hc;
    #pragma unroll
    for (int i = 0; i < 16; i++) hc[i] = 0.f;
    #pragma unroll
    for (int ks = 0; ks < 4; ks++) {
        const float* prw = &Ol[(rt * 32 + l31) * 68 + ks * 16 + 8 * lh];
        float4 pa = *(const float4*)prw;
        float4 pb = *(const float4*)(prw + 4);
        f16x8 bf;
        bf[0] = (f16)(pa.x * sclrow); bf[1] = (f16)(pa.y * sclrow);
        bf[2] = (f16)(pa.z * sclrow); bf[3] = (f16)(pa.w * sclrow);
        bf[4] = (f16)(pb.x * sclrow); bf[5] = (f16)(pb.y * sclrow);
        bf[6] = (f16)(pb.z * sclrow); bf[7] = (f16)(pb.w * sclrow);
        hc = __builtin_amdgcn_mfma_f32_32x32x16_f16(w1a[ks], bf, hc, 0, 0, 0);
    }
    #pragma unroll
    for (int g = 0; g < 4; g++) {
        union { f16 h[4]; uint2 u; } p;
        #pragma unroll
        for (int i = 0; i < 4; i++) {
            int hcol = ct * 32 + 8 * g + 4 * lh + i;
            p.h[i] = (f16)fmaxf(hc[4 * g + i] + sclrow * b1[hcol], 0.f);
        }
        *(uint2*)&MH.Hl[(rt * 32 + l31) * KS + ct * 32 + 8 * g + 4 * lh] = p.u;
    }
    __syncthreads();

    // ---- phase B: o_s^T = w2^T . h_s^T ; overwrite Ol ----
    f32x16 oc;
    #pragma unroll
    for (int i = 0; i < 16; i++) oc[i] = 0.f;
    #pragma unroll
    for (int ks = 0; ks < 4; ks++) {
        f16x8 bf = *(const f16x8*)&MH.Hl[(rt * 32 + l31) * KS + ks * 16 + 8 * lh];
        oc = __builtin_amdgcn_mfma_f32_32x32x16_f16(w2a[ks], bf, oc, 0, 0, 0);
    }
    __syncthreads();
    #pragma unroll
    for (int g = 0; g < 4; g++) {
        float4 o4 = make_float4(oc[4*g+0], oc[4*g+1], oc[4*g+2], oc[4*g+3]);
        *(float4*)&Ol[(rt * 32 + l31) * 68 + ct * 32 + 8 * g + 4 * lh] = o4;
    }
    __syncthreads();

    // ---- epilogue: s = o_s/s_n + b2 + residual; LayerNorm; guarded store ----
    float is = isls[r];
    float v[16];
    float sum = 0.f;
    #pragma unroll
    for (int i = 0; i < 16; i++) {
        int c = c0 + i;
        float x = Ol[r * 68 + c] * is + b2[c] + fv[i];
        v[i] = x; sum += x;
    }
    red[r][q][0] = sum;
    __syncthreads();
    float mu = (red[r][0][0] + red[r][1][0] + red[r][2][0] + red[r][3][0]) * (1.f / 64.f);
    float s2 = 0.f;
    #pragma unroll
    for (int i = 0; i < 16; i++) { float d = v[i] - mu; s2 += d * d; }
    red[r][q][1] = s2;
    __syncthreads();
    float var = (red[r][0][1] + red[r][1][1] + red[r][2][1] + red[r][3][1]) * (1.f / 64.f);
    float rs = rsqrtf(var + 1e-5f);
    if (n < NN) {
        size_t grow = (size_t)wdw * NN + n;
        #pragma unroll
        for (int i4 = 0; i4 < 4; i4++) {
            int c = c0 + 4 * i4;
            float4 g4 = *(const float4*)(gamma + c);
            float4 be = *(const float4*)(beta + c);
            float4 o4;
            o4.x = (v[4*i4+0] - mu) * rs * g4.x + be.x;
            o4.y = (v[4*i4+1] - mu) * rs * g4.y + be.y;
            o4.z = (v[4*i4+2] - mu) * rs * g4.z + be.z;
            o4.w = (v[4*i4+3] - mu) * rs * g4.w + be.w;
            *(float4*)(out + grow * DD + c) = o4;
        }
    }
}

// ---------------------------------------------------------------------------
extern "C" void kernel_launch(void* const* d_in, const int* in_sizes, int n_in,
                              void* d_out, int out_size, void* d_ws, size_t ws_size,
                              hipStream_t stream) {
    const float* feat    = (const float*)d_in[0];
    const float* weights = (const float*)d_in[1];
    const float* w1      = (const float*)d_in[2];
    const float* b1      = (const float*)d_in[3];
    const float* w2      = (const float*)d_in[4];
    const float* b2      = (const float*)d_in[5];
    const float* gamma   = (const float*)d_in[6];
    const float* beta    = (const float*)d_in[7];
    float* out = (float*)d_out;

    float* sigw   = (float*)d_ws;                   // 64
    float* invn   = sigw + 64;                      // 57600
    float* tspart = invn + BB * TT * NN;            // 960*64 = 61440
    f16*   w1f    = (f16*)(tspart + 960 * 64);      // 4096 f16
    f16*   w2f    = w1f + 4096;                     // 4096 f16
    float* Mt     = (float*)(w2f + 4096);           // 192*4096 = 786432 floats

    k_prep<<<BB * TT * 5 + 1, 256, 0, stream>>>(feat, weights, w1, w2,
                                                sigw, invn, tspart, w1f, w2f);
    k_M<<<BB * TT, 256, 0, stream>>>(feat, invn, Mt);
    k_U<<<NW * 5, 256, 0, stream>>>(feat, sigw, invn, tspart, Mt, w1f, w2f,
                                    b1, b2, gamma, beta, out);
}

// Round 13
// 102.401 us; speedup vs baseline: 1.3388x; 1.0424x over previous
//
#include <hip/hip_runtime.h>
#include <math.h>

#define BB  16
#define TT  12
#define T2C 10
#define NN  300
#define DD  64
#define M3  900   // 3*NN
#define NW  (BB*T2C)

typedef _Float16 f16;
typedef __attribute__((ext_vector_type(8)))  _Float16 f16x8;
typedef __attribute__((ext_vector_type(16))) float    f32x16;

#define KS 72   // fp16 row stride (144 B)

static __device__ inline unsigned pk2(f16 a, f16 b) {
    union { f16 h[2]; unsigned u; } x; x.h[0] = a; x.h[1] = b; return x.u;
}

// ---------------------------------------------------------------------------
// k_pm: fused prep + per-timestep gram. blk < 192: one block per (b,t):
//  per 64-row epoch (5): load feat once -> row-norm invn (LDS reduce) ->
//  pack Kti (feat*invn, [c][m]) + Vtt (raw, [d][m]) -> Mt MFMA accumulate;
//  tsum accumulated in registers (exact, no atomics/partials).
// blk == 192: sigw global + w1/w2 -> MFMA A-fragment order (fp16).
// ---------------------------------------------------------------------------
__global__ __launch_bounds__(256) void k_pm(const float* __restrict__ feat,
                                            const float* __restrict__ weights,
                                            const float* __restrict__ w1,
                                            const float* __restrict__ w2,
                                            float* __restrict__ sigw,
                                            float* __restrict__ invn,
                                            float* __restrict__ tsum,
                                            f16* __restrict__ w1f,
                                            f16* __restrict__ w2f,
                                            float* __restrict__ Mt) {
    int blk = blockIdx.x;
    int tid = threadIdx.x;

    if (blk == BB * TT) {
        if (tid < 64) sigw[tid] = 1.0f / (1.0f + expf(-weights[tid]));
        for (int p = tid; p < 1024; p += 256) {
            int lane = p & 63, s = p >> 6;
            int mat = s >> 3, loc = s & 7, ct = loc >> 2, ks = loc & 3;
            int hcol = ct * 32 + (lane & 31);
            const float* w = mat ? w2 : w1;
            f16* dst = (mat ? w2f : w1f) + ((size_t)loc * 64 + lane) * 8;
            f16x8 v;
            #pragma unroll
            for (int j = 0; j < 8; j++) {
                int d = ks * 16 + 8 * (lane >> 5) + j;
                v[j] = (f16)w[d * DD + hcol];
            }
            *(f16x8*)dst = v;
        }
        return;
    }

    __shared__ f16 Kti[64 * KS];     // [c][m] feat*invn
    __shared__ f16 Vtt[64 * KS];     // [d][m] raw feat
    __shared__ float sspart[64][8];  // row-norm partials
    __shared__ float invrow[64];
    __shared__ float tspp[32][64];   // tsum reduction buffer

    int bt = blk;
    int row0 = bt * NN;
    int wv = tid >> 6, lane = tid & 63;
    int l31 = lane & 31, lh = lane >> 5;
    int ci = wv & 1, di = wv >> 1;
    int mr = (tid & 31) * 2;         // staging m-pair
    int cb = (tid >> 5) * 8;         // staging 8-col block

    // sigmoid for this thread's 8 columns
    float sg[8];
    {
        float4 wv0 = *(const float4*)(weights + cb);
        float4 wv1 = *(const float4*)(weights + cb + 4);
        sg[0] = 1.f/(1.f+expf(-wv0.x)); sg[1] = 1.f/(1.f+expf(-wv0.y));
        sg[2] = 1.f/(1.f+expf(-wv0.z)); sg[3] = 1.f/(1.f+expf(-wv0.w));
        sg[4] = 1.f/(1.f+expf(-wv1.x)); sg[5] = 1.f/(1.f+expf(-wv1.y));
        sg[6] = 1.f/(1.f+expf(-wv1.z)); sg[7] = 1.f/(1.f+expf(-wv1.w));
    }

    float tacc[8];
    #pragma unroll
    for (int i = 0; i < 8; i++) tacc[i] = 0.f;
    f32x16 acc;
    #pragma unroll
    for (int i = 0; i < 16; i++) acc[i] = 0.f;

    for (int ep = 0; ep < 5; ep++) {
        __syncthreads();             // prev epoch MFMA reads done
        int gm0 = ep * 64 + mr, gm1 = gm0 + 1;
        bool ok0 = gm0 < NN, ok1 = gm1 < NN;
        int g0 = row0 + (ok0 ? gm0 : 0);
        int g1 = row0 + (ok1 ? gm1 : 0);
        float4 a0 = *(const float4*)(feat + (size_t)g0 * DD + cb);
        float4 a1 = *(const float4*)(feat + (size_t)g0 * DD + cb + 4);
        float4 b0 = *(const float4*)(feat + (size_t)g1 * DD + cb);
        float4 b1 = *(const float4*)(feat + (size_t)g1 * DD + cb + 4);
        float av[8] = {a0.x, a0.y, a0.z, a0.w, a1.x, a1.y, a1.z, a1.w};
        float bv[8] = {b0.x, b0.y, b0.z, b0.w, b1.x, b1.y, b1.z, b1.w};

        float ss0 = 0.f, ss1 = 0.f;
        #pragma unroll
        for (int i = 0; i < 8; i++) {
            float xa = av[i] * sg[i], xb = bv[i] * sg[i];
            ss0 += xa * xa; ss1 += xb * xb;
        }
        sspart[mr][tid >> 5] = ss0;
        sspart[mr + 1][tid >> 5] = ss1;
        __syncthreads();
        if (tid < 64) {
            float s = sspart[tid][0] + sspart[tid][1] + sspart[tid][2] + sspart[tid][3]
                    + sspart[tid][4] + sspart[tid][5] + sspart[tid][6] + sspart[tid][7];
            float in = 1.0f / fmaxf(sqrtf(s), 1e-12f);
            invrow[tid] = in;
            int grow = ep * 64 + tid;
            if (grow < NN) invn[row0 + grow] = in;
        }
        __syncthreads();
        float i0 = ok0 ? invrow[mr] : 0.f;
        float i1 = ok1 ? invrow[mr + 1] : 0.f;
        #pragma unroll
        for (int i = 0; i < 8; i++) {
            *(unsigned*)&Kti[(cb + i) * KS + mr] = pk2((f16)(av[i] * i0), (f16)(bv[i] * i1));
            *(unsigned*)&Vtt[(cb + i) * KS + mr] = pk2((f16)av[i], (f16)bv[i]);
            tacc[i] += av[i] * i0 + bv[i] * i1;
        }
        __syncthreads();
        #pragma unroll
        for (int ks = 0; ks < 4; ks++) {
            f16x8 af = *(const f16x8*)&Kti[(ci * 32 + l31) * KS + ks * 16 + 8 * lh];
            f16x8 bf = *(const f16x8*)&Vtt[(di * 32 + l31) * KS + ks * 16 + 8 * lh];
            acc = __builtin_amdgcn_mfma_f32_32x32x16_f16(af, bf, acc, 0, 0, 0);
        }
    }

    // Mt store: [d][c] fp32, C-layout (col d = di*32+l31, rows c consecutive)
    float* mb = Mt + (size_t)bt * 4096;
    #pragma unroll
    for (int g = 0; g < 4; g++)
        *(float4*)&mb[(di * 32 + l31) * 64 + ci * 32 + 8 * g + 4 * lh] =
            make_float4(acc[4 * g + 0], acc[4 * g + 1], acc[4 * g + 2], acc[4 * g + 3]);

    // tsum reduce: tsum[bt][d] = sigw[d] * sum_m feat[m][d]*invn[m]
    #pragma unroll
    for (int i = 0; i < 8; i++) tspp[tid & 31][cb + i] = tacc[i] * sg[i];
    __syncthreads();
    if (tid < 64) {
        float s = 0.f;
        #pragma unroll
        for (int g = 0; g < 32; g++) s += tspp[g][tid];
        tsum[(size_t)bt * 64 + tid] = s;
    }
}

// ---------------------------------------------------------------------------
// k_U (r12-verified): per (window, 64-row n-tile): M_w = 3-slab Mt sum ->
// fp16 Mh, U^T = Mh . Q''^T (4 MFMA), deg via tsum basis, Ol = U*dinv,
// then the verified FFN + residual + LayerNorm tail.
// ---------------------------------------------------------------------------
__global__ __launch_bounds__(256) void k_U(const float* __restrict__ feat,
                                           const float* __restrict__ sigw,
                                           const float* __restrict__ invn,
                                           const float* __restrict__ tsum,
                                           const float* __restrict__ Mt,
                                           const f16* __restrict__ w1f,
                                           const f16* __restrict__ w2f,
                                           const float* __restrict__ b1,
                                           const float* __restrict__ b2,
                                           const float* __restrict__ gamma,
                                           const float* __restrict__ beta,
                                           float* __restrict__ out) {
    __shared__ union __align__(16) {
        f16 Mh[64 * KS];
        f16 Hl[64 * KS];
    } MH;
    __shared__ float Ol[64 * 68];
    __shared__ float red[64][4][2];
    __shared__ float rmax[64][4];
    __shared__ float scls[64];
    __shared__ float isls[64];
    __shared__ float degp[64][4];
    __shared__ float degs[64];
    __shared__ float ksumL[64];

    int blk = blockIdx.x;
    int wdw = blk % NW;            // XCD swizzle
    int rb  = blk / NW;
    int t2 = wdw % T2C, b = wdw / T2C;
    int n0 = rb * 64;
    int qrow0 = (b * TT + t2 + 2) * NN;
    int tid = threadIdx.x;
    int wv = tid >> 6, lane = tid & 63;
    int l31 = lane & 31, lh = lane >> 5;
    int nt = wv & 1;
    int dt = wv >> 1;
    int ct = wv & 1, rt = wv >> 1;
    int r = tid >> 2, q = tid & 3, c0 = q * 16;

    f16x8 w1a[4], w2a[4];
    #pragma unroll
    for (int ks = 0; ks < 4; ks++) {
        w1a[ks] = *(const f16x8*)(w1f + ((size_t)(ct * 4 + ks) * 64 + lane) * 8);
        w2a[ks] = *(const f16x8*)(w2f + ((size_t)(ct * 4 + ks) * 64 + lane) * 8);
    }

    if (tid < 64) {
        const float* tp = tsum + (size_t)(b * TT + t2) * 64 + tid;
        ksumL[tid] = tp[0] + tp[64] + tp[128];
    }

    // Q'' B-frags: feat_q * sigw^2 * invn_q
    f16x8 qf[4];
    {
        int nloc = n0 + nt * 32 + l31;
        bool ok = nloc < NN;
        int gr = qrow0 + (ok ? nloc : 0);
        float in = ok ? invn[gr] : 0.f;
        #pragma unroll
        for (int ks = 0; ks < 4; ks++) {
            int cc = ks * 16 + 8 * lh;
            float4 f0 = *(const float4*)(feat + (size_t)gr * DD + cc);
            float4 f1 = *(const float4*)(feat + (size_t)gr * DD + cc + 4);
            float4 s0 = *(const float4*)(sigw + cc);
            float4 s1 = *(const float4*)(sigw + cc + 4);
            f16x8 qv;
            qv[0] = (f16)(f0.x * s0.x * s0.x * in); qv[1] = (f16)(f0.y * s0.y * s0.y * in);
            qv[2] = (f16)(f0.z * s0.z * s0.z * in); qv[3] = (f16)(f0.w * s0.w * s0.w * in);
            qv[4] = (f16)(f1.x * s1.x * s1.x * in); qv[5] = (f16)(f1.y * s1.y * s1.y * in);
            qv[6] = (f16)(f1.z * s1.z * s1.z * in); qv[7] = (f16)(f1.w * s1.w * s1.w * in);
            qf[ks] = qv;
        }
    }

    // M_w = sum of 3 Mt slabs (fp32)
    float ms[16];
    {
        const float* mtb = Mt + (size_t)(b * TT + t2) * 4096 + r * 64 + c0;
        #pragma unroll
        for (int i = 0; i < 4; i++) {
            float4 m0 = *(const float4*)(mtb + 4 * i);
            float4 m1 = *(const float4*)(mtb + 4096 + 4 * i);
            float4 m2 = *(const float4*)(mtb + 8192 + 4 * i);
            ms[4*i+0] = m0.x + m1.x + m2.x; ms[4*i+1] = m0.y + m1.y + m2.y;
            ms[4*i+2] = m0.z + m1.z + m2.z; ms[4*i+3] = m0.w + m1.w + m2.w;
        }
    }

    // residual feat rows + invq
    int n = n0 + r;
    int nc = (n < NN) ? n : (NN - 1);
    size_t frow = ((size_t)qrow0 + nc) * DD;
    float fv[16];
    #pragma unroll
    for (int i = 0; i < 4; i++) {
        float4 f = *(const float4*)(feat + frow + c0 + 4 * i);
        fv[4*i+0] = f.x; fv[4*i+1] = f.y; fv[4*i+2] = f.z; fv[4*i+3] = f.w;
    }
    float invq = invn[qrow0 + nc];

    __syncthreads();   // ksumL visible

    // deg partials
    {
        float p = 0.f;
        #pragma unroll
        for (int i = 0; i < 4; i++) {
            float4 s = *(const float4*)(sigw + c0 + 4 * i);
            float4 k = *(const float4*)(ksumL + c0 + 4 * i);
            p += fv[4*i+0] * s.x * k.x + fv[4*i+1] * s.y * k.y
               + fv[4*i+2] * s.z * k.z + fv[4*i+3] * s.w * k.w;
        }
        degp[r][q] = p * invq;
    }

    // Mh fp16 [d][c]
    #pragma unroll
    for (int hhalf = 0; hhalf < 2; hhalf++) {
        f16x8 v;
        #pragma unroll
        for (int j = 0; j < 8; j++) v[j] = (f16)ms[8 * hhalf + j];
        *(f16x8*)&MH.Mh[r * KS + c0 + 8 * hhalf] = v;
    }
    __syncthreads();

    if (tid < 64)
        degs[tid] = degp[tid][0] + degp[tid][1] + degp[tid][2] + degp[tid][3];

    // U^T tile: D[d][n] = sum_c M(c,d) Q''(n,c)
    f32x16 ua;
    #pragma unroll
    for (int i = 0; i < 16; i++) ua[i] = 0.f;
    #pragma unroll
    for (int ks = 0; ks < 4; ks++) {
        f16x8 af = *(const f16x8*)&MH.Mh[(dt * 32 + l31) * KS + ks * 16 + 8 * lh];
        ua = __builtin_amdgcn_mfma_f32_32x32x16_f16(af, qf[ks], ua, 0, 0, 0);
    }
    __syncthreads();

    // Ol[n][d] = U * dinv
    {
        int nl = nt * 32 + l31;
        float dg = degs[nl];
        float dinv = (dg == 0.f) ? 0.f : 1.f / dg;
        #pragma unroll
        for (int g = 0; g < 4; g++)
            *(float4*)&Ol[nl * 68 + dt * 32 + 8 * g + 4 * lh] =
                make_float4(ua[4*g+0] * dinv, ua[4*g+1] * dinv,
                            ua[4*g+2] * dinv, ua[4*g+3] * dinv);
    }
    __syncthreads();

    // per-row pow2 scale
    {
        float mx = 0.f;
        #pragma unroll
        for (int i = 0; i < 16; i += 4) {
            float4 f = *(const float4*)&Ol[r * 68 + c0 + i];
            mx = fmaxf(mx, fmaxf(fmaxf(fabsf(f.x), fabsf(f.y)),
                                 fmaxf(fabsf(f.z), fabsf(f.w))));
        }
        rmax[r][q] = mx;
    }
    __syncthreads();
    if (q == 0) {
        float rm = fmaxf(fmaxf(rmax[r][0], rmax[r][1]),
                         fmaxf(rmax[r][2], rmax[r][3]));
        int e = 0;
        frexpf(rm, &e);
        scls[r] = (rm > 1.f) ? exp2f((float)-e) : 1.f;
        isls[r] = (rm > 1.f) ? exp2f((float)e) : 1.f;
    }
    __syncthreads();

    // phase A: h_s^T = w1^T . A_s^T
    float sclrow = scls[rt * 32 + l31];
    f32x16 hc;
    #pragma unroll
    for (int i = 0; i < 16; i++) hc[i] = 0.f;
    #pragma unroll
    for (int ks = 0; ks < 4; ks++) {
        const float* prw = &Ol[(rt * 32 + l31) * 68 + ks * 16 + 8 * lh];
        float4 pa = *(const float4*)prw;
        float4 pb = *(const float4*)(prw + 4);
        f16x8 bf;
        bf[0] = (f16)(pa.x * sclrow); bf[1] = (f16)(pa.y * sclrow);
        bf[2] = (f16)(pa.z * sclrow); bf[3] = (f16)(pa.w * sclrow);
        bf[4] = (f16)(pb.x * sclrow); bf[5] = (f16)(pb.y * sclrow);
        bf[6] = (f16)(pb.z * sclrow); bf[7] = (f16)(pb.w * sclrow);
        hc = __builtin_amdgcn_mfma_f32_32x32x16_f16(w1a[ks], bf, hc, 0, 0, 0);
    }
    #pragma unroll
    for (int g = 0; g < 4; g++) {
        union { f16 h[4]; uint2 u; } p;
        #pragma unroll
        for (int i = 0; i < 4; i++) {
            int hcol = ct * 32 + 8 * g + 4 * lh + i;
            p.h[i] = (f16)fmaxf(hc[4 * g + i] + sclrow * b1[hcol], 0.f);
        }
        *(uint2*)&MH.Hl[(rt * 32 + l31) * KS + ct * 32 + 8 * g + 4 * lh] = p.u;
    }
    __syncthreads();

    // phase B: o_s^T = w2^T . h_s^T ; overwrite Ol
    f32x16 oc;
    #pragma unroll
    for (int i = 0; i < 16; i++) oc[i] = 0.f;
    #pragma unroll
    for (int ks = 0; ks < 4; ks++) {
        f16x8 bf = *(const f16x8*)&MH.Hl[(rt * 32 + l31) * KS + ks * 16 + 8 * lh];
        oc = __builtin_amdgcn_mfma_f32_32x32x16_f16(w2a[ks], bf, oc, 0, 0, 0);
    }
    __syncthreads();
    #pragma unroll
    for (int g = 0; g < 4; g++) {
        float4 o4 = make_float4(oc[4*g+0], oc[4*g+1], oc[4*g+2], oc[4*g+3]);
        *(float4*)&Ol[(rt * 32 + l31) * 68 + ct * 32 + 8 * g + 4 * lh] = o4;
    }
    __syncthreads();

    // epilogue: s = o_s/s_n + b2 + residual; LayerNorm; guarded store
    float is = isls[r];
    float v[16];
    float sum = 0.f;
    #pragma unroll
    for (int i = 0; i < 16; i++) {
        int c = c0 + i;
        float x = Ol[r * 68 + c] * is + b2[c] + fv[i];
        v[i] = x; sum += x;
    }
    red[r][q][0] = sum;
    __syncthreads();
    float mu = (red[r][0][0] + red[r][1][0] + red[r][2][0] + red[r][3][0]) * (1.f / 64.f);
    float s2 = 0.f;
    #pragma unroll
    for (int i = 0; i < 16; i++) { float d = v[i] - mu; s2 += d * d; }
    red[r][q][1] = s2;
    __syncthreads();
    float var = (red[r][0][1] + red[r][1][1] + red[r][2][1] + red[r][3][1]) * (1.f / 64.f);
    float rs = rsqrtf(var + 1e-5f);
    if (n < NN) {
        size_t grow = (size_t)wdw * NN + n;
        #pragma unroll
        for (int i4 = 0; i4 < 4; i4++) {
            int c = c0 + 4 * i4;
            float4 g4 = *(const float4*)(gamma + c);
            float4 be = *(const float4*)(beta + c);
            float4 o4;
            o4.x = (v[4*i4+0] - mu) * rs * g4.x + be.x;
            o4.y = (v[4*i4+1] - mu) * rs * g4.y + be.y;
            o4.z = (v[4*i4+2] - mu) * rs * g4.z + be.z;
            o4.w = (v[4*i4+3] - mu) * rs * g4.w + be.w;
            *(float4*)(out + grow * DD + c) = o4;
        }
    }
}

// ---------------------------------------------------------------------------
extern "C" void kernel_launch(void* const* d_in, const int* in_sizes, int n_in,
                              void* d_out, int out_size, void* d_ws, size_t ws_size,
                              hipStream_t stream) {
    const float* feat    = (const float*)d_in[0];
    const float* weights = (const float*)d_in[1];
    const float* w1      = (const float*)d_in[2];
    const float* b1      = (const float*)d_in[3];
    const float* w2      = (const float*)d_in[4];
    const float* b2      = (const float*)d_in[5];
    const float* gamma   = (const float*)d_in[6];
    const float* beta    = (const float*)d_in[7];
    float* out = (float*)d_out;

    float* sigw = (float*)d_ws;                 // 64
    float* invn = sigw + 64;                    // 57600
    float* tsum = invn + BB * TT * NN;          // 192*64 = 12288
    f16*   w1f  = (f16*)(tsum + BB * TT * DD);  // 4096 f16
    f16*   w2f  = w1f + 4096;                   // 4096 f16
    float* Mt   = (float*)(w2f + 4096);         // 192*4096 floats

    k_pm<<<BB * TT + 1, 256, 0, stream>>>(feat, weights, w1, w2, sigw, invn,
                                          tsum, w1f, w2f, Mt);
    k_U<<<NW * 5, 256, 0, stream>>>(feat, sigw, invn, tsum, Mt, w1f, w2f,
                                    b1, b2, gamma, beta, out);
}